// Round 1
// 2471.722 us; speedup vs baseline: 1.0881x; 1.0881x over previous
//
#include <hip/hip_runtime.h>
#include <math.h>
#include <stdint.h>

// Problem: T=128, B=32, E=H=1024, V=C=32000. Gates order [i,f,g,o].
typedef unsigned int u32;
typedef __attribute__((__ext_vector_type__(4))) float f32x4;
typedef __attribute__((__ext_vector_type__(8))) __bf16 bf16x8;
typedef __attribute__((__ext_vector_type__(4))) __bf16 bf16x4;

#define AS1 __attribute__((address_space(1)))
#define AS3 __attribute__((address_space(3)))

__device__ __forceinline__ void cp16(const void* g, void* l) {
    // async global->LDS, 16B per lane; LDS dest = uniform base + lane*16
    __builtin_amdgcn_global_load_lds((const AS1 u32*)g, (AS3 u32*)l, 16, 0, 0);
}

// ---------------- init: zero hs slab 0 (h_{-1}=0) and barrier flags ---------
// flags: 128 blocks x 32 u32 (128B pad each) = 4096 words = 16 KB
__global__ __launch_bounds__(256) void initk(u32* hs0, u32* bar) {
    int i = blockIdx.x * 256 + threadIdx.x;  // grid 64 -> 16384 threads
    hs0[i] = 0;
    if (i < 4096) bar[i] = 0;
}

// ---------------- embedding gather + cast to bf16 ---------------------------
__global__ __launch_bounds__(256) void embed_cast(const int* __restrict__ toks,
                                                  const float* __restrict__ emb,
                                                  __bf16* __restrict__ X) {
    const int row = blockIdx.x;            // t*32+b
    const int tok = toks[row];
    const float4 v = *(const float4*)(emb + (long)tok * 1024 + threadIdx.x * 4);
    bf16x4 o;
    o.x = (__bf16)v.x; o.y = (__bf16)v.y; o.z = (__bf16)v.z; o.w = (__bf16)v.w;
    *(bf16x4*)(X + (long)row * 1024 + threadIdx.x * 4) = o;
}

// ---------------- transpose [K=1024, N] fp32 -> [N, 1024] bf16 --------------
__global__ __launch_bounds__(256) void tcast(const float* __restrict__ W,
                                             __bf16* __restrict__ Wt, int N) {
    __shared__ float ld[64][65];           // +1 pad: conflict-free transpose
    const int tid = threadIdx.x;
    const int q = tid >> 6, l = tid & 63;
    const long n0 = (long)blockIdx.x * 64;
    const long k0 = (long)blockIdx.y * 64;
#pragma unroll
    for (int r = q; r < 64; r += 4) ld[r][l] = W[(k0 + r) * N + n0 + l];
    __syncthreads();
#pragma unroll
    for (int r = q; r < 64; r += 4)
        Wt[(n0 + r) * 1024 + k0 + l] = (__bf16)ld[l][r];
}

// ---------------- m97-style 128x128 GEMM: C[M,N] = A[M,K] * Bt[N,K]^T + bias -
// K = 1024 fixed. 256 threads = 4 waves, each wave a 64x64 quadrant.
__global__ __launch_bounds__(256) void gemm_bt(const __bf16* __restrict__ A,
                                               const __bf16* __restrict__ Bt,
                                               const float* __restrict__ bias,
                                               float* __restrict__ Cmat, int Ncols) {
    __shared__ __bf16 As[128 * 64];
    __shared__ __bf16 Bs[128 * 64];
    const int tid = threadIdx.x;
    const int wave = tid >> 6, lane = tid & 63;
    const int quad = lane >> 4, l16 = lane & 15;
    const int wm = wave & 1, wn = wave >> 1;
    const long Mb = (long)blockIdx.y * 128;
    const long Nb = (long)blockIdx.x * 128;

    f32x4 acc[4][4] = {};

    const int r8 = lane >> 3;              // 8 rows per wave-instr
    const int c16 = (lane & 7) * 16;       // 16B chunk within 128B row
    const char* Abase = (const char*)(A + Mb * 1024) + (wave * 32 + r8) * 2048 + c16;
    const char* Bbase = (const char*)(Bt + Nb * 1024) + (wave * 32 + r8) * 2048 + c16;
    __bf16* AsW = As + (wave * 32) * 64;
    __bf16* BsW = Bs + (wave * 32) * 64;

    for (int k0 = 0; k0 < 1024; k0 += 64) {
#pragma unroll
        for (int j = 0; j < 4; ++j) {
            cp16(Abase + j * 8 * 2048 + k0 * 2, AsW + j * 8 * 64);
            cp16(Bbase + j * 8 * 2048 + k0 * 2, BsW + j * 8 * 64);
        }
        __syncthreads();   // drains vmcnt for global_load_lds
        const __bf16* Ar = As + (wm * 64 + l16) * 64 + quad * 8;
        const __bf16* Br = Bs + (wn * 64 + l16) * 64 + quad * 8;
#pragma unroll
        for (int ks = 0; ks < 2; ++ks) {
            bf16x8 af[4], bfr[4];
#pragma unroll
            for (int i = 0; i < 4; ++i) af[i] = *(const bf16x8*)(Ar + i * 16 * 64 + ks * 32);
#pragma unroll
            for (int i = 0; i < 4; ++i) bfr[i] = *(const bf16x8*)(Br + i * 16 * 64 + ks * 32);
#pragma unroll
            for (int mi = 0; mi < 4; ++mi)
#pragma unroll
                for (int ni = 0; ni < 4; ++ni)
                    acc[mi][ni] = __builtin_amdgcn_mfma_f32_16x16x32_bf16(
                        af[mi], bfr[ni], acc[mi][ni], 0, 0, 0);
        }
        __syncthreads();
    }
    // epilogue: C/D layout col=lane&15, row=quad*4+reg
#pragma unroll
    for (int ni = 0; ni < 4; ++ni) {
        const long col = Nb + wn * 64 + ni * 16 + l16;
        const float bo = bias[col];
#pragma unroll
        for (int mi = 0; mi < 4; ++mi) {
            const long row = Mb + wm * 64 + mi * 16 + quad * 4;
#pragma unroll
            for (int r = 0; r < 4; ++r)
                Cmat[(row + r) * (long)Ncols + col] = acc[mi][ni][r] + bo;
        }
    }
}

// ---------------- persistent LSTM recurrence --------------------------------
// 128 blocks x 256 thr. Block wg owns h-cols [wg*8, wg*8+8) => 32 gate cols,
// LDS slab order [i0..7 | f0..7 | g0..7 | o0..7]. Waves split K (256 each),
// all 4 (mtile,ntile) tiles per wave; partials summed via LDS in pointwise.
//
// Grid barrier: contention-free flag barrier. Each block release-stores its
// generation (t+1, monotonic -> no reset) to its OWN 128B-padded flag word;
// 128 threads poll one flag each with relaxed agent-scope loads (bypass L2,
// observe remote XCD stores), then one acquire fence invalidates L1/L2 so
// the next step's hs reads see remote writes. Replaces the single-address
// atomic_fetch_add chain (128 serialized cross-XCD RMWs ~= 12 us/step).
__device__ __forceinline__ void grid_barrier(u32* flags, int tid, int wg, u32 gen) {
    __syncthreads();                       // all lanes' h-stores drained (vmcnt0)
    if (tid == 0) {
        __builtin_amdgcn_fence(__ATOMIC_RELEASE, "agent");   // wb L2 -> agent-visible
        __hip_atomic_store(&flags[(u32)wg << 5], gen, __ATOMIC_RELAXED,
                           __HIP_MEMORY_SCOPE_AGENT);
    }
    if (tid < (int)gridDim.x) {
        const u32* fp = flags + ((u32)tid << 5);
        while (__hip_atomic_load(fp, __ATOMIC_RELAXED, __HIP_MEMORY_SCOPE_AGENT) < gen) {}
    }
    __syncthreads();
    __builtin_amdgcn_fence(__ATOMIC_ACQUIRE, "agent");       // inv L1/L2
}

__global__ __launch_bounds__(256, 1) void lstm_rec(const float* __restrict__ gpre,  // [4096][4096]
                                                   const __bf16* __restrict__ Wht,  // [4096][1024]
                                                   __bf16* __restrict__ hs,         // [129*32][1024]
                                                   u32* __restrict__ bar) {
    __shared__ float gbuf[4][4][256];      // [wave][tile(mt*2+nt)][m*16+n]
    const int tid = threadIdx.x;
    const int wave = tid >> 6, lane = tid & 63;
    const int quad = lane >> 4, l16 = lane & 15;
    const int wg = blockIdx.x;
    const int kw = wave * 256;             // this wave's K range

    // W_h fragments live in registers for all 128 steps (64 VGPRs)
    bf16x8 wf[2][8];
#pragma unroll
    for (int nt = 0; nt < 2; ++nt) {
        const int scol = nt * 16 + l16;
        const long gcol = (long)(scol >> 3) * 1024 + wg * 8 + (scol & 7);
        const __bf16* wp = Wht + gcol * 1024 + kw + quad * 8;
#pragma unroll
        for (int ks = 0; ks < 8; ++ks) wf[nt][ks] = *(const bf16x8*)(wp + ks * 32);
    }

    float c = 0.f;                          // cell state: registers for all t
    const int prow = tid >> 3, pcol = tid & 7;
    const float* gp0 = gpre + (long)wg * 8 + pcol;
    __bf16* hout = hs + (long)32 * 1024 + (long)prow * 1024 + wg * 8 + pcol;

    for (int t = 0; t < 128; ++t) {
        // prefetch this thread's 4 gate pre-activations (HBM, issued early)
        const float* gp = gp0 + ((long)t * 32 + prow) * 4096;
        float gpr[4];
#pragma unroll
        for (int gi = 0; gi < 4; ++gi) gpr[gi] = gp[gi * 1024];

        // A-fragments of h_t straight from global (L2/L3-hot, 64KB/CU/step)
        const __bf16* hp = hs + ((long)t * 32) * 1024 + kw + quad * 8;
        bf16x8 af[2][8];
#pragma unroll
        for (int mt = 0; mt < 2; ++mt) {
            const __bf16* hp2 = hp + (mt * 16 + l16) * 1024;
#pragma unroll
            for (int ks = 0; ks < 8; ++ks) af[mt][ks] = *(const bf16x8*)(hp2 + ks * 32);
        }
        f32x4 acc[2][2] = {};
#pragma unroll
        for (int ks = 0; ks < 8; ++ks)
#pragma unroll
            for (int mt = 0; mt < 2; ++mt)
#pragma unroll
                for (int nt = 0; nt < 2; ++nt)
                    acc[mt][nt] = __builtin_amdgcn_mfma_f32_16x16x32_bf16(
                        af[mt][ks], wf[nt][ks], acc[mt][nt], 0, 0, 0);
#pragma unroll
        for (int mt = 0; mt < 2; ++mt)
#pragma unroll
            for (int nt = 0; nt < 2; ++nt)
#pragma unroll
                for (int r = 0; r < 4; ++r)
                    gbuf[wave][mt * 2 + nt][(quad * 4 + r) * 16 + l16] = acc[mt][nt][r];
        __syncthreads();

        // pointwise LSTM cell for (row=prow, h-col=wg*8+pcol)
        {
            const int mt = prow >> 4, rr = prow & 15;
            float g4[4];
#pragma unroll
            for (int gi = 0; gi < 4; ++gi) {
                const int scol = gi * 8 + pcol;
                const int nt = scol >> 4, cc = scol & 15;
                float s = gpr[gi];
                const int tile = mt * 2 + nt, elem = rr * 16 + cc;
#pragma unroll
                for (int w = 0; w < 4; ++w) s += gbuf[w][tile][elem];
                g4[gi] = s;
            }
            const float ig = 1.f / (1.f + expf(-g4[0]));
            const float fg = 1.f / (1.f + expf(-g4[1]));
            const float gg = tanhf(g4[2]);
            const float og = 1.f / (1.f + expf(-g4[3]));
            c = fg * c + ig * gg;
            const float h = og * tanhf(c);
            hout[(long)t * 32 * 1024] = (__bf16)h;   // hs slab t+1
        }
        if (t != 127) grid_barrier(bar, tid, wg, (u32)t + 1u);
    }
}

// ---------------- launch ----------------------------------------------------
extern "C" void kernel_launch(void* const* d_in, const int* in_sizes, int n_in,
                              void* d_out, int out_size, void* d_ws, size_t ws_size,
                              hipStream_t stream) {
    const int* toks = (const int*)d_in[0];
    const float* emb = (const float*)d_in[1];
    const float* Wx = (const float*)d_in[2];
    const float* Wh = (const float*)d_in[3];
    const float* b = (const float*)d_in[4];
    const float* Wo = (const float*)d_in[5];
    const float* bo = (const float*)d_in[6];
    float* out = (float*)d_out;
    char* ws = (char*)d_ws;

    // ws layout (bytes), total ~158.6 MB (+16 KB barrier flags)
    __bf16* X    = (__bf16*)(ws + 0);           //  8 MB  [4096][1024]
    __bf16* Wxt  = (__bf16*)(ws + 8388608);     //  8 MB  [4096][1024]
    __bf16* Wht  = (__bf16*)(ws + 16777216);    //  8 MB  [4096][1024]
    __bf16* Wot  = (__bf16*)(ws + 25165824);    // 64 MB  [32000][1024]
    float*  gpre = (float*)(ws + 90701824);     // 64 MB  [4096][4096]
    __bf16* hs   = (__bf16*)(ws + 157810688);   //  8 MB  [129*32][1024]
    u32*    bar  = (u32*)(ws + 166264832);      // 16 KB  128 x 128B flags

    initk<<<64, 256, 0, stream>>>((u32*)hs, bar);
    embed_cast<<<4096, 256, 0, stream>>>(toks, emb, X);
    {
        dim3 g(64, 16);
        tcast<<<g, 256, 0, stream>>>(Wx, Wxt, 4096);
        tcast<<<g, 256, 0, stream>>>(Wh, Wht, 4096);
    }
    {
        dim3 g(500, 16);
        tcast<<<g, 256, 0, stream>>>(Wo, Wot, 32000);
    }
    {
        dim3 g(32, 32);
        gemm_bt<<<g, 256, 0, stream>>>(X, Wxt, b, gpre, 4096);
    }
    lstm_rec<<<128, 256, 0, stream>>>(gpre, Wht, hs, bar);
    {
        dim3 g(250, 32);
        gemm_bt<<<g, 250 * 0 + 256, 0, stream>>>(hs + 32 * 1024, Wot, bo, out, 32000);
    }
}